// Round 2
// baseline (16516.895 us; speedup 1.0000x reference)
//
#include <hip/hip_runtime.h>

typedef unsigned short u16;

__device__ __forceinline__ float b2f(u16 u){
  unsigned x = ((unsigned)u) << 16;
  return __uint_as_float(x);
}

__device__ __forceinline__ float wred_sum(float v){
  #pragma unroll
  for (int o = 32; o > 0; o >>= 1) v += __shfl_down(v, o, 64);
  return v;
}
__device__ __forceinline__ float wred_max(float v){
  #pragma unroll
  for (int o = 32; o > 0; o >>= 1) v = fmaxf(v, __shfl_down(v, o, 64));
  return v;
}

// runtime-dtype loads: bf=1 -> buffer is bf16 (u16), bf=0 -> f32. Element index i.
__device__ __forceinline__ void ldv4(const void* p, size_t i, int bf, float* d){
  if (bf){
    ushort4 v = *(const ushort4*)((const u16*)p + i);
    d[0]=b2f(v.x); d[1]=b2f(v.y); d[2]=b2f(v.z); d[3]=b2f(v.w);
  } else {
    float4 v = *(const float4*)((const float*)p + i);
    d[0]=v.x; d[1]=v.y; d[2]=v.z; d[3]=v.w;
  }
}
__device__ __forceinline__ float ldv1(const void* p, size_t i, int bf){
  return bf ? b2f(((const u16*)p)[i]) : ((const float*)p)[i];
}

__global__ void zero2(float* p){ if (threadIdx.x < 2) p[threadIdx.x] = 0.0f; }

// Decide whether float-typed inputs are bf16 (flag=1) or f32 (flag=0).
// bf16 N(0,1): |x| <= ~6. f32 read as u16s: even u16s are random mantissa
// bits -> ~47% decode to |x|>100 or NaN.
__global__ void detect_dtype(const u16* __restrict__ enc, float* __restrict__ flagp){
  if (threadIdx.x == 0){
    int cnt = 0;
    for (int i = 0; i < 512; ++i){
      float v = b2f(enc[i]);
      if (!(fabsf(v) <= 100.0f)) ++cnt;   // NaN counts as huge
    }
    flagp[2] = (cnt > 16) ? 0.0f : 1.0f;
  }
}

__global__ __launch_bounds__(256) void upcast_flag(const void* __restrict__ in,
                                                   float4* __restrict__ out, int n4,
                                                   const float* __restrict__ flagp){
  int bf = (flagp[2] != 0.0f);
  int i = blockIdx.x * 256 + threadIdx.x;
  if (i < n4){
    if (bf){
      ushort4 u = ((const ushort4*)in)[i];
      out[i] = make_float4(b2f(u.x), b2f(u.y), b2f(u.z), b2f(u.w));
    } else {
      out[i] = ((const float4*)in)[i];
    }
  }
}

// C[4096,N] = X[4096,K] @ W[N,K]^T + bias, optional relu. W/bias dtype per flag,
// addressed by ELEMENT offset wOff/bOff from base. X,C f32 in workspace.
__global__ __launch_bounds__(256) void gemm_w(
    const float* __restrict__ X, const void* __restrict__ W, size_t wOff,
    const void* __restrict__ bias, size_t bOff, float* __restrict__ C,
    int N, int K, int ldx, int ldc, int relu, const float* __restrict__ flagp)
{
  int wbf = (flagp[2] != 0.0f);
  __shared__ float As[8][132];
  __shared__ float Bs[8][132];
  int tid = threadIdx.x;
  int tx = tid & 15, ty = tid >> 4;
  int bm0 = blockIdx.y * 128, bn0 = blockIdx.x * 128;
  int arow = tid >> 1;          // 0..127
  int acol = (tid & 1) * 4;     // 0 or 4
  const float* Xb = X + (size_t)bm0 * ldx;
  float acc[8][8] = {};
  for (int k0 = 0; k0 < K; k0 += 8){
    float xa[4], wa[4];
    {
      float4 v = *(const float4*)(Xb + (size_t)arow * ldx + k0 + acol);
      xa[0]=v.x; xa[1]=v.y; xa[2]=v.z; xa[3]=v.w;
    }
    ldv4(W, wOff + (size_t)(bn0 + arow) * K + k0 + acol, wbf, wa);
    __syncthreads();
    #pragma unroll
    for (int j = 0; j < 4; ++j){ As[acol+j][arow] = xa[j]; Bs[acol+j][arow] = wa[j]; }
    __syncthreads();
    #pragma unroll
    for (int kk = 0; kk < 8; ++kk){
      float a[8], b[8];
      *(float4*)&a[0] = *(const float4*)&As[kk][ty*8];
      *(float4*)&a[4] = *(const float4*)&As[kk][ty*8+4];
      *(float4*)&b[0] = *(const float4*)&Bs[kk][tx*8];
      *(float4*)&b[4] = *(const float4*)&Bs[kk][tx*8+4];
      #pragma unroll
      for (int i = 0; i < 8; ++i)
        #pragma unroll
        for (int j = 0; j < 8; ++j)
          acc[i][j] = fmaf(a[i], b[j], acc[i][j]);
    }
  }
  float bv[8];
  #pragma unroll
  for (int j = 0; j < 8; ++j) bv[j] = b2f(0), bv[j] = ldv1(bias, bOff + bn0 + tx*8 + j, wbf);
  #pragma unroll
  for (int i = 0; i < 8; ++i){
    int row = bm0 + ty*8 + i;
    #pragma unroll
    for (int j = 0; j < 8; ++j){
      float v = acc[i][j] + bv[j];
      if (relu) v = fmaxf(v, 0.0f);
      C[(size_t)row * ldc + (bn0 + tx*8 + j)] = v;
    }
  }
}

// scores[bh,q,k] = 0.125 * Q[b,q,h,:] . K[b,k,h,:]; batched 128 over z, f32 only.
__global__ __launch_bounds__(256) void gemm_qk(
    const float* __restrict__ Q, const float* __restrict__ Km, float* __restrict__ S)
{
  int bh = blockIdx.z;
  int b = bh >> 4, h = bh & 15;
  size_t offQ = (size_t)b * 512 * 1024 + (size_t)h * 64;
  size_t offC = (size_t)bh * 512 * 512;
  __shared__ float As[8][132];
  __shared__ float Bs[8][132];
  int tid = threadIdx.x;
  int tx = tid & 15, ty = tid >> 4;
  int bm0 = blockIdx.y * 128, bn0 = blockIdx.x * 128;
  int arow = tid >> 1;
  int acol = (tid & 1) * 4;
  float acc[8][8] = {};
  for (int k0 = 0; k0 < 64; k0 += 8){
    float4 xa = *(const float4*)(Q  + offQ + (size_t)(bm0 + arow) * 1024 + k0 + acol);
    float4 wa = *(const float4*)(Km + offQ + (size_t)(bn0 + arow) * 1024 + k0 + acol);
    __syncthreads();
    As[acol+0][arow]=xa.x; As[acol+1][arow]=xa.y; As[acol+2][arow]=xa.z; As[acol+3][arow]=xa.w;
    Bs[acol+0][arow]=wa.x; Bs[acol+1][arow]=wa.y; Bs[acol+2][arow]=wa.z; Bs[acol+3][arow]=wa.w;
    __syncthreads();
    #pragma unroll
    for (int kk = 0; kk < 8; ++kk){
      float a[8], b2[8];
      *(float4*)&a[0]  = *(const float4*)&As[kk][ty*8];
      *(float4*)&a[4]  = *(const float4*)&As[kk][ty*8+4];
      *(float4*)&b2[0] = *(const float4*)&Bs[kk][tx*8];
      *(float4*)&b2[4] = *(const float4*)&Bs[kk][tx*8+4];
      #pragma unroll
      for (int i = 0; i < 8; ++i)
        #pragma unroll
        for (int j = 0; j < 8; ++j)
          acc[i][j] = fmaf(a[i], b2[j], acc[i][j]);
    }
  }
  #pragma unroll
  for (int i = 0; i < 8; ++i)
    #pragma unroll
    for (int j = 0; j < 8; ++j)
      S[offC + (size_t)(bm0 + ty*8 + i) * 512 + (bn0 + tx*8 + j)] = acc[i][j] * 0.125f;
}

__global__ __launch_bounds__(256) void softmax512(float* __restrict__ S){
  size_t base = (size_t)blockIdx.x * 512;
  int tid = threadIdx.x;
  float a = S[base + tid], b = S[base + tid + 256];
  __shared__ float red[4];
  float m = wred_max(fmaxf(a, b));
  if ((tid & 63) == 0) red[tid >> 6] = m;
  __syncthreads();
  float bm = fmaxf(fmaxf(red[0], red[1]), fmaxf(red[2], red[3]));
  __syncthreads();
  float e0 = expf(a - bm), e1 = expf(b - bm);
  float s = wred_sum(e0 + e1);
  if ((tid & 63) == 0) red[tid >> 6] = s;
  __syncthreads();
  float inv = 1.0f / (red[0] + red[1] + red[2] + red[3]);
  S[base + tid] = e0 * inv;
  S[base + tid + 256] = e1 * inv;
}

// ctx[b,q,h,:] = sum_k P[bh,q,k] * V[b,k,h,:]
__global__ __launch_bounds__(256) void attn_ctx(
    const float* __restrict__ P, const float* __restrict__ V, float* __restrict__ O)
{
  int bh = blockIdx.z;
  int b = bh >> 4, h = bh & 15;
  const float* Pp = P + (size_t)bh * 512 * 512;
  const float* Vp = V + (size_t)b * 512 * 1024 + h * 64;
  float*       Op = O + (size_t)b * 512 * 1024 + h * 64;
  int q0 = blockIdx.y * 64;
  __shared__ float As[16][68];
  __shared__ float Bs[16][68];
  int tid = threadIdx.x;
  int tx = tid & 15, ty = tid >> 4;
  int arow = tid >> 2;
  int acol = (tid & 3) * 4;
  int vrow = tid >> 4;
  int vcol = (tid & 15) * 4;
  float acc[4][4] = {};
  for (int k0 = 0; k0 < 512; k0 += 16){
    float4 pv = *(const float4*)(Pp + (size_t)(q0 + arow) * 512 + k0 + acol);
    float4 vv = *(const float4*)(Vp + (size_t)(k0 + vrow) * 1024 + vcol);
    __syncthreads();
    As[acol+0][arow] = pv.x; As[acol+1][arow] = pv.y;
    As[acol+2][arow] = pv.z; As[acol+3][arow] = pv.w;
    *(float4*)&Bs[vrow][vcol] = vv;
    __syncthreads();
    #pragma unroll
    for (int kk = 0; kk < 16; ++kk){
      float a[4], b[4];
      *(float4*)a = *(const float4*)&As[kk][ty*4];
      *(float4*)b = *(const float4*)&Bs[kk][tx*4];
      #pragma unroll
      for (int i = 0; i < 4; ++i)
        #pragma unroll
        for (int j = 0; j < 4; ++j)
          acc[i][j] = fmaf(a[i], b[j], acc[i][j]);
    }
  }
  #pragma unroll
  for (int i = 0; i < 4; ++i)
    #pragma unroll
    for (int j = 0; j < 4; ++j)
      Op[(size_t)(q0 + ty*4 + i) * 1024 + tx*4 + j] = acc[i][j];
}

// out = LN(x1+x2)*g + b ; g,b element-offset eo, dtype per flag
__global__ __launch_bounds__(256) void ln_off(
    const float* __restrict__ x1, const float* __restrict__ x2,
    const void* __restrict__ g, const void* __restrict__ b, size_t eo,
    float* __restrict__ out, const float* __restrict__ flagp)
{
  int bf = (flagp[2] != 0.0f);
  int row = blockIdx.x, tid = threadIdx.x;
  size_t base = (size_t)row * 1024;
  float v[4]; float s = 0.0f;
  #pragma unroll
  for (int j = 0; j < 4; ++j){
    int c = tid + j * 256;
    v[j] = x1[base + c] + x2[base + c];
    s += v[j];
  }
  __shared__ float red[4];
  s = wred_sum(s);
  if ((tid & 63) == 0) red[tid >> 6] = s;
  __syncthreads();
  float mean = (red[0] + red[1] + red[2] + red[3]) * (1.0f / 1024.0f);
  __syncthreads();
  float sq = 0.0f;
  #pragma unroll
  for (int j = 0; j < 4; ++j){ float d = v[j] - mean; sq += d * d; }
  sq = wred_sum(sq);
  if ((tid & 63) == 0) red[tid >> 6] = sq;
  __syncthreads();
  float inv = rsqrtf((red[0] + red[1] + red[2] + red[3]) * (1.0f / 1024.0f) + 1e-5f);
  #pragma unroll
  for (int j = 0; j < 4; ++j){
    int c = tid + j * 256;
    out[base + c] = (v[j] - mean) * inv * ldv1(g, eo + c, bf) + ldv1(b, eo + c, bf);
  }
}

__global__ __launch_bounds__(256) void loss_row(
    const float* __restrict__ A, const void* __restrict__ cls_w, const void* __restrict__ cls_b,
    const int* __restrict__ labels, const int* __restrict__ maskA, const int* __restrict__ cand,
    float* __restrict__ acc, float* __restrict__ out, const float* __restrict__ flagp)
{
  int bf = (flagp[2] != 0.0f);
  int r = blockIdx.x, tid = threadIdx.x;
  const float* a = A + (size_t)r * 1024;
  float s0 = 0.0f, s1 = 0.0f;
  #pragma unroll
  for (int j = 0; j < 4; ++j){
    int c = tid + j * 256;
    float x = a[c];
    s0 += x * ldv1(cls_w, c, bf);
    s1 += x * ldv1(cls_w, 1024 + c, bf);
  }
  __shared__ float red0[4], red1[4];
  s0 = wred_sum(s0); s1 = wred_sum(s1);
  if ((tid & 63) == 0){ red0[tid >> 6] = s0; red1[tid >> 6] = s1; }
  __syncthreads();
  if (tid == 0){
    float e0 = red0[0] + red0[1] + red0[2] + red0[3] + ldv1(cls_b, 0, bf);
    float e1 = red1[0] + red1[1] + red1[2] + red1[3] + ldv1(cls_b, 1, bf);
    int lab = labels[r];
    float m = fmaxf(e0, e1);
    float lse = m + logf(expf(e0 - m) + expf(e1 - m));
    float ce = lse - (lab == 1 ? e1 : e0);
    float w = (lab == 1) ? 5.0f : 1.0f;
    if (maskA[r] == 1){
      atomicAdd(acc, ce * w);
      atomicAdd(acc + 1, 1.0f);
    }
    int pred = (e1 > e0) ? 1 : 0;
    out[1 + r] = (cand[r] == 1 && pred == 1) ? 1.0f : 0.0f;
  }
}

__global__ void finalize1(const float* __restrict__ acc, float* __restrict__ out){
  out[0] = acc[0] / fmaxf(acc[1], 1.0f);
}

extern "C" void kernel_launch(void* const* d_in, const int* in_sizes, int n_in,
                              void* d_out, int out_size, void* d_ws, size_t ws_size,
                              hipStream_t stream)
{
  const void* enc   = d_in[0];
  const void* desc  = d_in[1];
  const int* maskA  = (const int*)d_in[2];
  const int* cand   = (const int*)d_in[3];
  const int* labels = (const int*)d_in[4];
  const void* ipw   = d_in[5];
  const void* ipb   = d_in[6];
  const void* outw  = d_in[7];
  const void* outb  = d_in[8];
  const void* ln1g  = d_in[9];
  const void* ln1b  = d_in[10];
  const void* fw1   = d_in[11];
  const void* fb1   = d_in[12];
  const void* fw2   = d_in[13];
  const void* fb2   = d_in[14];
  const void* ln2g  = d_in[15];
  const void* ln2b  = d_in[16];
  const void* clsw  = d_in[17];
  const void* clsb  = d_in[18];
  float* out = (float*)d_out;

  const int E = 1024, F = 4096, Lc = 9;
  const size_t NE = (size_t)4096 * 1024;
  float* ws   = (float*)d_ws;
  float* Abuf = ws;                                  // current activation (4096,E)
  float* Bf   = Abuf + NE;                           // describe upcast (4096,E)
  float* Qb   = Bf + NE;                             // Q / ctx / ffn-out
  float* Kb   = Qb + NE;                             // K / attn_out
  float* Vb   = Kb + NE;                             // V / A1
  float* Sc   = Vb + NE;                             // scores (128,512,512)
  float* FFb  = Sc + (size_t)128 * 512 * 512;        // ffn mid (4096,F)
  float* acc  = FFb + (size_t)4096 * 4096;           // [sum, count, dtype-flag]

  zero2<<<1, 64, 0, stream>>>(acc);
  detect_dtype<<<1, 64, 0, stream>>>((const u16*)enc, acc);
  upcast_flag<<<4096, 256, 0, stream>>>(enc,  (float4*)Abuf, (int)(NE / 4), acc);
  upcast_flag<<<4096, 256, 0, stream>>>(desc, (float4*)Bf,   (int)(NE / 4), acc);

  dim3 gP(8, 32, 1);     // N=1024 tiles x M=4096 tiles
  dim3 gF1(32, 32, 1);   // N=4096
  for (int l = 0; l < Lc; ++l){
    size_t oQ  = (size_t)l * 3 * E * E;
    size_t oK  = oQ + (size_t)E * E;
    size_t oV  = oK + (size_t)E * E;
    size_t obQ = (size_t)l * 3 * E;

    gemm_w<<<gP, 256, 0, stream>>>(Abuf, ipw, oQ, ipb, obQ,     Qb, 1024, 1024, 1024, 1024, 0, acc);
    gemm_w<<<gP, 256, 0, stream>>>(Bf,   ipw, oK, ipb, obQ + E, Kb, 1024, 1024, 1024, 1024, 0, acc);
    gemm_w<<<gP, 256, 0, stream>>>(Bf,   ipw, oV, ipb, obQ + 2*E, Vb, 1024, 1024, 1024, 1024, 0, acc);

    gemm_qk<<<dim3(4,4,128), 256, 0, stream>>>(Qb, Kb, Sc);
    softmax512<<<65536, 256, 0, stream>>>(Sc);
    attn_ctx<<<dim3(1,8,128), 256, 0, stream>>>(Sc, Vb, Qb);     // ctx -> Qb

    gemm_w<<<gP, 256, 0, stream>>>(Qb, outw, (size_t)l*E*E, outb, (size_t)l*E,
                                   Kb, 1024, 1024, 1024, 1024, 0, acc);
    ln_off<<<4096, 256, 0, stream>>>(Abuf, Kb, ln1g, ln1b, (size_t)l*E, Vb, acc);   // A1 -> Vb
    gemm_w<<<gF1, 256, 0, stream>>>(Vb, fw1, (size_t)l*F*E, fb1, (size_t)l*F,
                                    FFb, 4096, 1024, 1024, 4096, 1, acc);
    gemm_w<<<gP, 256, 0, stream>>>(FFb, fw2, (size_t)l*E*F, fb2, (size_t)l*E,
                                   Qb, 1024, 4096, 4096, 1024, 0, acc);
    ln_off<<<4096, 256, 0, stream>>>(Vb, Qb, ln2g, ln2b, (size_t)l*E, Abuf, acc);   // A2 -> Abuf
  }

  loss_row<<<4096, 256, 0, stream>>>(Abuf, clsw, clsb, labels, maskA, cand, acc, out, acc);
  finalize1<<<1, 1, 0, stream>>>(acc, out);
}

// Round 3
// 9553.614 us; speedup vs baseline: 1.7289x; 1.7289x over previous
//
#include <hip/hip_runtime.h>

typedef unsigned short u16;
typedef __attribute__((ext_vector_type(8))) short bfrag;   // 8 bf16 (4 VGPRs)
typedef __attribute__((ext_vector_type(4))) float f32x4;

__device__ __forceinline__ float b2f(u16 u){
  unsigned x = ((unsigned)u) << 16;
  return __uint_as_float(x);
}
__device__ __forceinline__ u16 f2b_rn(float f){
  unsigned x = __float_as_uint(f);
  unsigned r = x + 0x7FFFu + ((x >> 16) & 1u);
  return (u16)(r >> 16);
}

__device__ __forceinline__ float wred_sum(float v){
  #pragma unroll
  for (int o = 32; o > 0; o >>= 1) v += __shfl_down(v, o, 64);
  return v;
}
__device__ __forceinline__ float wred_max(float v){
  #pragma unroll
  for (int o = 32; o > 0; o >>= 1) v = fmaxf(v, __shfl_down(v, o, 64));
  return v;
}

// runtime-dtype loads: bf=1 -> buffer is bf16 (u16), bf=0 -> f32. Element index i.
__device__ __forceinline__ float ldv1(const void* p, size_t i, int bf){
  return bf ? b2f(((const u16*)p)[i]) : ((const float*)p)[i];
}

__global__ void zero2(float* p){ if (threadIdx.x < 2) p[threadIdx.x] = 0.0f; }

// bf16 N(0,1): |x| <= ~6. f32 read as u16s: even u16s are random mantissa
// bits -> ~47% decode to |x|>100 or NaN.
__global__ void detect_dtype(const u16* __restrict__ enc, float* __restrict__ flagp){
  if (threadIdx.x == 0){
    int cnt = 0;
    for (int i = 0; i < 512; ++i){
      float v = b2f(enc[i]);
      if (!(fabsf(v) <= 100.0f)) ++cnt;
    }
    flagp[2] = (cnt > 16) ? 0.0f : 1.0f;
  }
}

__global__ __launch_bounds__(256) void upcast_flag(const void* __restrict__ in,
                                                   float4* __restrict__ out, int n4,
                                                   const float* __restrict__ flagp){
  int bf = (flagp[2] != 0.0f);
  int i = blockIdx.x * 256 + threadIdx.x;
  if (i < n4){
    if (bf){
      ushort4 u = ((const ushort4*)in)[i];
      out[i] = make_float4(b2f(u.x), b2f(u.y), b2f(u.z), b2f(u.w));
    } else {
      out[i] = ((const float4*)in)[i];
    }
  }
}

// MFMA NT-GEMM: C[4096,N] = X[4096,K] @ W[N,K]^T + bias, optional relu.
// X f32 (ws, row stride K); W bf16 or f32 per flag (element offset wOff, row
// stride K); C f32 (row stride ldc). f32 X is hi/lo-split into bf16 pairs ->
// 2 MFMAs (exact-bf16 W) or 3 MFMAs (f32 W, also hi/lo split).
// Tile 128x128, 4 waves of 64x64, BK=32. LDS rows padded to 40 u16 (bank
// stride 20 -> <=2-way conflicts, free).
__global__ __launch_bounds__(256) void gemm_mfma(
    const float* __restrict__ X, const void* __restrict__ W, size_t wOff,
    const void* __restrict__ bias, size_t bOff, float* __restrict__ C,
    int K, int ldc, int relu, const float* __restrict__ flagp)
{
  const int wbf = (flagp[2] != 0.0f);
  __shared__ u16 Ah[128][40];
  __shared__ u16 Al[128][40];
  __shared__ u16 Wh[128][40];
  __shared__ u16 Wl[128][40];

  const int tid  = threadIdx.x;
  const int bm0  = blockIdx.y * 128, bn0 = blockIdx.x * 128;
  const int srow = tid >> 1;            // 0..127
  const int scol = (tid & 1) * 16;      // 0 or 16
  const int w    = tid >> 6;
  const int lane = tid & 63;
  const int q    = lane >> 4;           // quad 0..3
  const int t16  = lane & 15;
  const int wm   = (w & 1) * 64;
  const int wn   = (w >> 1) * 64;

  f32x4 acc[4][4];
  #pragma unroll
  for (int mi = 0; mi < 4; ++mi)
    #pragma unroll
    for (int ni = 0; ni < 4; ++ni)
      acc[mi][ni] = (f32x4){0.f, 0.f, 0.f, 0.f};

  const float* Xrow = X + (size_t)(bm0 + srow) * K + scol;

  for (int k0 = 0; k0 < K; k0 += 32){
    // ---- load globals into regs ----
    float4 xv[4];
    #pragma unroll
    for (int j = 0; j < 4; ++j)
      xv[j] = *(const float4*)(Xrow + k0 + j * 4);

    bfrag wv_bf[2];
    float4 wv_f[4];
    if (wbf){
      const u16* Wr = (const u16*)W + wOff + (size_t)(bn0 + srow) * K + k0 + scol;
      wv_bf[0] = *(const bfrag*)(Wr);
      wv_bf[1] = *(const bfrag*)(Wr + 8);
    } else {
      const float* Wr = (const float*)W + wOff + (size_t)(bn0 + srow) * K + k0 + scol;
      #pragma unroll
      for (int j = 0; j < 4; ++j) wv_f[j] = *(const float4*)(Wr + j * 4);
    }

    __syncthreads();   // prior iteration's LDS reads done

    // ---- stage A (hi/lo split) ----
    #pragma unroll
    for (int j = 0; j < 4; ++j){
      float xs[4] = {xv[j].x, xv[j].y, xv[j].z, xv[j].w};
      ushort4 h, lo;
      u16* hp = &h.x; u16* lp = &lo.x;
      #pragma unroll
      for (int e = 0; e < 4; ++e){
        u16 hb = f2b_rn(xs[e]);
        hp[e] = hb;
        lp[e] = f2b_rn(xs[e] - b2f(hb));
      }
      *(ushort4*)&Ah[srow][scol + j * 4] = h;
      *(ushort4*)&Al[srow][scol + j * 4] = lo;
    }
    // ---- stage W ----
    if (wbf){
      *(bfrag*)&Wh[srow][scol]     = wv_bf[0];
      *(bfrag*)&Wh[srow][scol + 8] = wv_bf[1];
    } else {
      #pragma unroll
      for (int j = 0; j < 4; ++j){
        float xs[4] = {wv_f[j].x, wv_f[j].y, wv_f[j].z, wv_f[j].w};
        ushort4 h, lo;
        u16* hp = &h.x; u16* lp = &lo.x;
        #pragma unroll
        for (int e = 0; e < 4; ++e){
          u16 hb = f2b_rn(xs[e]);
          hp[e] = hb;
          lp[e] = f2b_rn(xs[e] - b2f(hb));
        }
        *(ushort4*)&Wh[srow][scol + j * 4] = h;
        *(ushort4*)&Wl[srow][scol + j * 4] = lo;
      }
    }
    __syncthreads();

    // ---- compute ----
    bfrag ah[4], al[4], bh[4];
    #pragma unroll
    for (int mi = 0; mi < 4; ++mi){
      ah[mi] = *(const bfrag*)&Ah[wm + mi * 16 + t16][q * 8];
      al[mi] = *(const bfrag*)&Al[wm + mi * 16 + t16][q * 8];
    }
    #pragma unroll
    for (int ni = 0; ni < 4; ++ni)
      bh[ni] = *(const bfrag*)&Wh[wn + ni * 16 + t16][q * 8];

    if (wbf){
      #pragma unroll
      for (int mi = 0; mi < 4; ++mi)
        #pragma unroll
        for (int ni = 0; ni < 4; ++ni){
          acc[mi][ni] = __builtin_amdgcn_mfma_f32_16x16x32_bf16(ah[mi], bh[ni], acc[mi][ni], 0, 0, 0);
          acc[mi][ni] = __builtin_amdgcn_mfma_f32_16x16x32_bf16(al[mi], bh[ni], acc[mi][ni], 0, 0, 0);
        }
    } else {
      bfrag bl[4];
      #pragma unroll
      for (int ni = 0; ni < 4; ++ni)
        bl[ni] = *(const bfrag*)&Wl[wn + ni * 16 + t16][q * 8];
      #pragma unroll
      for (int mi = 0; mi < 4; ++mi)
        #pragma unroll
        for (int ni = 0; ni < 4; ++ni){
          acc[mi][ni] = __builtin_amdgcn_mfma_f32_16x16x32_bf16(ah[mi], bh[ni], acc[mi][ni], 0, 0, 0);
          acc[mi][ni] = __builtin_amdgcn_mfma_f32_16x16x32_bf16(al[mi], bh[ni], acc[mi][ni], 0, 0, 0);
          acc[mi][ni] = __builtin_amdgcn_mfma_f32_16x16x32_bf16(ah[mi], bl[ni], acc[mi][ni], 0, 0, 0);
        }
    }
  }

  // ---- epilogue: C[row = bm0+wm+mi*16+q*4+r][col = bn0+wn+ni*16+t16] ----
  float bv[4];
  #pragma unroll
  for (int ni = 0; ni < 4; ++ni)
    bv[ni] = ldv1(bias, bOff + bn0 + wn + ni * 16 + t16, wbf);
  #pragma unroll
  for (int mi = 0; mi < 4; ++mi){
    #pragma unroll
    for (int r = 0; r < 4; ++r){
      int row = bm0 + wm + mi * 16 + q * 4 + r;
      float* Cr = C + (size_t)row * ldc + bn0 + wn;
      #pragma unroll
      for (int ni = 0; ni < 4; ++ni){
        float v = acc[mi][ni][r] + bv[ni];
        if (relu) v = fmaxf(v, 0.0f);
        Cr[ni * 16 + t16] = v;
      }
    }
  }
}

// scores[bh,q,k] = 0.125 * Q[b,q,h,:] . K[b,k,h,:]; batched 128 over z, f32.
__global__ __launch_bounds__(256) void gemm_qk(
    const float* __restrict__ Q, const float* __restrict__ Km, float* __restrict__ S)
{
  int bh = blockIdx.z;
  int b = bh >> 4, h = bh & 15;
  size_t offQ = (size_t)b * 512 * 1024 + (size_t)h * 64;
  size_t offC = (size_t)bh * 512 * 512;
  __shared__ float As[8][132];
  __shared__ float Bs[8][132];
  int tid = threadIdx.x;
  int tx = tid & 15, ty = tid >> 4;
  int bm0 = blockIdx.y * 128, bn0 = blockIdx.x * 128;
  int arow = tid >> 1;
  int acol = (tid & 1) * 4;
  float acc[8][8] = {};
  for (int k0 = 0; k0 < 64; k0 += 8){
    float4 xa = *(const float4*)(Q  + offQ + (size_t)(bm0 + arow) * 1024 + k0 + acol);
    float4 wa = *(const float4*)(Km + offQ + (size_t)(bn0 + arow) * 1024 + k0 + acol);
    __syncthreads();
    As[acol+0][arow]=xa.x; As[acol+1][arow]=xa.y; As[acol+2][arow]=xa.z; As[acol+3][arow]=xa.w;
    Bs[acol+0][arow]=wa.x; Bs[acol+1][arow]=wa.y; Bs[acol+2][arow]=wa.z; Bs[acol+3][arow]=wa.w;
    __syncthreads();
    #pragma unroll
    for (int kk = 0; kk < 8; ++kk){
      float a[8], b2[8];
      *(float4*)&a[0]  = *(const float4*)&As[kk][ty*8];
      *(float4*)&a[4]  = *(const float4*)&As[kk][ty*8+4];
      *(float4*)&b2[0] = *(const float4*)&Bs[kk][tx*8];
      *(float4*)&b2[4] = *(const float4*)&Bs[kk][tx*8+4];
      #pragma unroll
      for (int i = 0; i < 8; ++i)
        #pragma unroll
        for (int j = 0; j < 8; ++j)
          acc[i][j] = fmaf(a[i], b2[j], acc[i][j]);
    }
  }
  #pragma unroll
  for (int i = 0; i < 8; ++i)
    #pragma unroll
    for (int j = 0; j < 8; ++j)
      S[offC + (size_t)(bm0 + ty*8 + i) * 512 + (bn0 + tx*8 + j)] = acc[i][j] * 0.125f;
}

__global__ __launch_bounds__(256) void softmax512(float* __restrict__ S){
  size_t base = (size_t)blockIdx.x * 512;
  int tid = threadIdx.x;
  float a = S[base + tid], b = S[base + tid + 256];
  __shared__ float red[4];
  float m = wred_max(fmaxf(a, b));
  if ((tid & 63) == 0) red[tid >> 6] = m;
  __syncthreads();
  float bm = fmaxf(fmaxf(red[0], red[1]), fmaxf(red[2], red[3]));
  __syncthreads();
  float e0 = expf(a - bm), e1 = expf(b - bm);
  float s = wred_sum(e0 + e1);
  if ((tid & 63) == 0) red[tid >> 6] = s;
  __syncthreads();
  float inv = 1.0f / (red[0] + red[1] + red[2] + red[3]);
  S[base + tid] = e0 * inv;
  S[base + tid + 256] = e1 * inv;
}

// ctx[b,q,h,:] = sum_k P[bh,q,k] * V[b,k,h,:]
__global__ __launch_bounds__(256) void attn_ctx(
    const float* __restrict__ P, const float* __restrict__ V, float* __restrict__ O)
{
  int bh = blockIdx.z;
  int b = bh >> 4, h = bh & 15;
  const float* Pp = P + (size_t)bh * 512 * 512;
  const float* Vp = V + (size_t)b * 512 * 1024 + h * 64;
  float*       Op = O + (size_t)b * 512 * 1024 + h * 64;
  int q0 = blockIdx.y * 64;
  __shared__ float As[16][68];
  __shared__ float Bs[16][68];
  int tid = threadIdx.x;
  int tx = tid & 15, ty = tid >> 4;
  int arow = tid >> 2;
  int acol = (tid & 3) * 4;
  int vrow = tid >> 4;
  int vcol = (tid & 15) * 4;
  float acc[4][4] = {};
  for (int k0 = 0; k0 < 512; k0 += 16){
    float4 pv = *(const float4*)(Pp + (size_t)(q0 + arow) * 512 + k0 + acol);
    float4 vv = *(const float4*)(Vp + (size_t)(k0 + vrow) * 1024 + vcol);
    __syncthreads();
    As[acol+0][arow] = pv.x; As[acol+1][arow] = pv.y;
    As[acol+2][arow] = pv.z; As[acol+3][arow] = pv.w;
    *(float4*)&Bs[vrow][vcol] = vv;
    __syncthreads();
    #pragma unroll
    for (int kk = 0; kk < 16; ++kk){
      float a[4], b[4];
      *(float4*)a = *(const float4*)&As[kk][ty*4];
      *(float4*)b = *(const float4*)&Bs[kk][tx*4];
      #pragma unroll
      for (int i = 0; i < 4; ++i)
        #pragma unroll
        for (int j = 0; j < 4; ++j)
          acc[i][j] = fmaf(a[i], b[j], acc[i][j]);
    }
  }
  #pragma unroll
  for (int i = 0; i < 4; ++i)
    #pragma unroll
    for (int j = 0; j < 4; ++j)
      Op[(size_t)(q0 + ty*4 + i) * 1024 + tx*4 + j] = acc[i][j];
}

// out = LN(x1+x2)*g + b ; g,b element-offset eo, dtype per flag
__global__ __launch_bounds__(256) void ln_off(
    const float* __restrict__ x1, const float* __restrict__ x2,
    const void* __restrict__ g, const void* __restrict__ b, size_t eo,
    float* __restrict__ out, const float* __restrict__ flagp)
{
  int bf = (flagp[2] != 0.0f);
  int row = blockIdx.x, tid = threadIdx.x;
  size_t base = (size_t)row * 1024;
  float v[4]; float s = 0.0f;
  #pragma unroll
  for (int j = 0; j < 4; ++j){
    int c = tid + j * 256;
    v[j] = x1[base + c] + x2[base + c];
    s += v[j];
  }
  __shared__ float red[4];
  s = wred_sum(s);
  if ((tid & 63) == 0) red[tid >> 6] = s;
  __syncthreads();
  float mean = (red[0] + red[1] + red[2] + red[3]) * (1.0f / 1024.0f);
  __syncthreads();
  float sq = 0.0f;
  #pragma unroll
  for (int j = 0; j < 4; ++j){ float d = v[j] - mean; sq += d * d; }
  sq = wred_sum(sq);
  if ((tid & 63) == 0) red[tid >> 6] = sq;
  __syncthreads();
  float inv = rsqrtf((red[0] + red[1] + red[2] + red[3]) * (1.0f / 1024.0f) + 1e-5f);
  #pragma unroll
  for (int j = 0; j < 4; ++j){
    int c = tid + j * 256;
    out[base + c] = (v[j] - mean) * inv * ldv1(g, eo + c, bf) + ldv1(b, eo + c, bf);
  }
}

__global__ __launch_bounds__(256) void loss_row(
    const float* __restrict__ A, const void* __restrict__ cls_w, const void* __restrict__ cls_b,
    const int* __restrict__ labels, const int* __restrict__ maskA, const int* __restrict__ cand,
    float* __restrict__ acc, float* __restrict__ out, const float* __restrict__ flagp)
{
  int bf = (flagp[2] != 0.0f);
  int r = blockIdx.x, tid = threadIdx.x;
  const float* a = A + (size_t)r * 1024;
  float s0 = 0.0f, s1 = 0.0f;
  #pragma unroll
  for (int j = 0; j < 4; ++j){
    int c = tid + j * 256;
    float x = a[c];
    s0 += x * ldv1(cls_w, c, bf);
    s1 += x * ldv1(cls_w, 1024 + c, bf);
  }
  __shared__ float red0[4], red1[4];
  s0 = wred_sum(s0); s1 = wred_sum(s1);
  if ((tid & 63) == 0){ red0[tid >> 6] = s0; red1[tid >> 6] = s1; }
  __syncthreads();
  if (tid == 0){
    float e0 = red0[0] + red0[1] + red0[2] + red0[3] + ldv1(cls_b, 0, bf);
    float e1 = red1[0] + red1[1] + red1[2] + red1[3] + ldv1(cls_b, 1, bf);
    int lab = labels[r];
    float m = fmaxf(e0, e1);
    float lse = m + logf(expf(e0 - m) + expf(e1 - m));
    float ce = lse - (lab == 1 ? e1 : e0);
    float w = (lab == 1) ? 5.0f : 1.0f;
    if (maskA[r] == 1){
      atomicAdd(acc, ce * w);
      atomicAdd(acc + 1, 1.0f);
    }
    int pred = (e1 > e0) ? 1 : 0;
    out[1 + r] = (cand[r] == 1 && pred == 1) ? 1.0f : 0.0f;
  }
}

__global__ void finalize1(const float* __restrict__ acc, float* __restrict__ out){
  out[0] = acc[0] / fmaxf(acc[1], 1.0f);
}

extern "C" void kernel_launch(void* const* d_in, const int* in_sizes, int n_in,
                              void* d_out, int out_size, void* d_ws, size_t ws_size,
                              hipStream_t stream)
{
  const void* enc   = d_in[0];
  const void* desc  = d_in[1];
  const int* maskA  = (const int*)d_in[2];
  const int* cand   = (const int*)d_in[3];
  const int* labels = (const int*)d_in[4];
  const void* ipw   = d_in[5];
  const void* ipb   = d_in[6];
  const void* outw  = d_in[7];
  const void* outb  = d_in[8];
  const void* ln1g  = d_in[9];
  const void* ln1b  = d_in[10];
  const void* fw1   = d_in[11];
  const void* fb1   = d_in[12];
  const void* fw2   = d_in[13];
  const void* fb2   = d_in[14];
  const void* ln2g  = d_in[15];
  const void* ln2b  = d_in[16];
  const void* clsw  = d_in[17];
  const void* clsb  = d_in[18];
  float* out = (float*)d_out;

  const int E = 1024, F = 4096, Lc = 9;
  const size_t NE = (size_t)4096 * 1024;
  float* ws   = (float*)d_ws;
  float* Abuf = ws;                                  // current activation (4096,E)
  float* Bf   = Abuf + NE;                           // describe upcast (4096,E)
  float* Qb   = Bf + NE;                             // Q / ctx / ffn-out
  float* Kb   = Qb + NE;                             // K / attn_out
  float* Vb   = Kb + NE;                             // V / A1
  float* Sc   = Vb + NE;                             // scores (128,512,512)
  float* FFb  = Sc + (size_t)128 * 512 * 512;        // ffn mid (4096,F)
  float* acc  = FFb + (size_t)4096 * 4096;           // [sum, count, dtype-flag]

  zero2<<<1, 64, 0, stream>>>(acc);
  detect_dtype<<<1, 64, 0, stream>>>((const u16*)enc, acc);
  upcast_flag<<<4096, 256, 0, stream>>>(enc,  (float4*)Abuf, (int)(NE / 4), acc);
  upcast_flag<<<4096, 256, 0, stream>>>(desc, (float4*)Bf,   (int)(NE / 4), acc);

  dim3 gP(8, 32, 1);     // N=1024
  dim3 gF1(32, 32, 1);   // N=4096
  for (int l = 0; l < Lc; ++l){
    size_t oQ  = (size_t)l * 3 * E * E;
    size_t oK  = oQ + (size_t)E * E;
    size_t oV  = oK + (size_t)E * E;
    size_t obQ = (size_t)l * 3 * E;

    gemm_mfma<<<gP, 256, 0, stream>>>(Abuf, ipw, oQ,       ipb, obQ,       Qb, 1024, 1024, 0, acc);
    gemm_mfma<<<gP, 256, 0, stream>>>(Bf,   ipw, oK,       ipb, obQ + E,   Kb, 1024, 1024, 0, acc);
    gemm_mfma<<<gP, 256, 0, stream>>>(Bf,   ipw, oV,       ipb, obQ + 2*E, Vb, 1024, 1024, 0, acc);

    gemm_qk<<<dim3(4,4,128), 256, 0, stream>>>(Qb, Kb, Sc);
    softmax512<<<65536, 256, 0, stream>>>(Sc);
    attn_ctx<<<dim3(1,8,128), 256, 0, stream>>>(Sc, Vb, Qb);     // ctx -> Qb

    gemm_mfma<<<gP, 256, 0, stream>>>(Qb, outw, (size_t)l*E*E, outb, (size_t)l*E,
                                      Kb, 1024, 1024, 0, acc);
    ln_off<<<4096, 256, 0, stream>>>(Abuf, Kb, ln1g, ln1b, (size_t)l*E, Vb, acc);   // A1 -> Vb
    gemm_mfma<<<gF1, 256, 0, stream>>>(Vb, fw1, (size_t)l*F*E, fb1, (size_t)l*F,
                                       FFb, 1024, 4096, 1, acc);
    gemm_mfma<<<gP, 256, 0, stream>>>(FFb, fw2, (size_t)l*E*F, fb2, (size_t)l*E,
                                      Qb, 4096, 1024, 0, acc);
    ln_off<<<4096, 256, 0, stream>>>(Vb, Qb, ln2g, ln2b, (size_t)l*E, Abuf, acc);   // A2 -> Abuf
  }

  loss_row<<<4096, 256, 0, stream>>>(Abuf, clsw, clsb, labels, maskA, cand, acc, out, acc);
  finalize1<<<1, 1, 0, stream>>>(acc, out);
}